// Round 1
// baseline (543.155 us; speedup 1.0000x reference)
//
#include <hip/hip_runtime.h>
#include <math.h>

namespace {
constexpr int BN   = 8192;                // batch columns
constexpr int DK   = 128;                 // feature dim
constexpr int NCAT = 8192;                // cat rows
constexpr int SRC  = 4;                   // source chunks
constexpr int RG   = 8;                   // row groups (1024 rows each, 2 per chunk)
constexpr int ROWS_PER_G = NCAT / RG;     // 1024
constexpr int CWG  = 64;                  // columns per workgroup
constexpr int RT   = 64;                  // row tile
constexpr int PAD  = 132;                 // padded LDS row stride in floats (16B aligned)
}

__device__ __forceinline__ float4 ld4(const float* p) {
    return *reinterpret_cast<const float4*>(p);
}
__device__ __forceinline__ void fma4(float& acc, const float4& a, const float4& b) {
    acc += a.x * b.x;
    acc += a.y * b.y;
    acc += a.z * b.z;
    acc += a.w * b.w;
}

// Pass 1: partial sum(d^4) and max(d) per (rowgroup, column)
__global__ __launch_bounds__(256) void k_pass1(const float* __restrict__ x,
                                               const float* __restrict__ cat,
                                               float* __restrict__ pp4,
                                               float* __restrict__ pmax) {
    __shared__ float xs[CWG * PAD];
    __shared__ float cs[RT * PAD];
    __shared__ float redA[16 * CWG];
    __shared__ float redB[16 * CWG];

    const int t = threadIdx.x;
    const int colbase = blockIdx.x * CWG;
    const int rowbase = blockIdx.y * ROWS_PER_G;

    // stage x tile: 64 cols x 128
    for (int li = t * 4; li < CWG * DK; li += 256 * 4) {
        const int c = li >> 7, k = li & 127;
        *reinterpret_cast<float4*>(&xs[c * PAD + k]) =
            ld4(&x[(size_t)(colbase + c) * DK + k]);
    }

    const int cl = t & 15;   // owns cols cl + 16*j
    const int rl = t >> 4;   // owns rows rl*4 + i

    float p4[4] = {0.f, 0.f, 0.f, 0.f};
    float mx[4] = {-1e30f, -1e30f, -1e30f, -1e30f};

    for (int rt0 = 0; rt0 < ROWS_PER_G; rt0 += RT) {
        __syncthreads();
        for (int li = t * 4; li < RT * DK; li += 256 * 4) {
            const int r = li >> 7, k = li & 127;
            *reinterpret_cast<float4*>(&cs[r * PAD + k]) =
                ld4(&cat[(size_t)(rowbase + rt0 + r) * DK + k]);
        }
        __syncthreads();

        float d[4][4] = {};
#pragma unroll 4
        for (int k = 0; k < DK; k += 4) {
            float4 A[4], Bv[4];
#pragma unroll
            for (int i = 0; i < 4; ++i) A[i] = ld4(&cs[(rl * 4 + i) * PAD + k]);
#pragma unroll
            for (int j = 0; j < 4; ++j) Bv[j] = ld4(&xs[(cl + 16 * j) * PAD + k]);
#pragma unroll
            for (int i = 0; i < 4; ++i)
#pragma unroll
                for (int j = 0; j < 4; ++j) fma4(d[i][j], A[i], Bv[j]);
        }
#pragma unroll
        for (int i = 0; i < 4; ++i)
#pragma unroll
            for (int j = 0; j < 4; ++j) {
                const float v = d[i][j];
                const float v2 = v * v;
                p4[j] += v2 * v2;
                mx[j] = fmaxf(mx[j], v);
            }
    }

    __syncthreads();
#pragma unroll
    for (int j = 0; j < 4; ++j) {
        redA[rl * CWG + cl + 16 * j] = p4[j];
        redB[rl * CWG + cl + 16 * j] = mx[j];
    }
    __syncthreads();
    if (t < CWG) {
        float sp = 0.f, sm = -1e30f;
#pragma unroll
        for (int r = 0; r < 16; ++r) {
            sp += redA[r * CWG + t];
            sm = fmaxf(sm, redB[r * CWG + t]);
        }
        pp4[(size_t)blockIdx.y * BN + colbase + t] = sp;
        pmax[(size_t)blockIdx.y * BN + colbase + t] = sm;
    }
}

// Reduce partials -> inv_norm, scaled max
__global__ __launch_bounds__(256) void k_norm(const float* __restrict__ pp4,
                                              const float* __restrict__ pmax,
                                              float* __restrict__ inv_norm,
                                              float* __restrict__ vmax) {
    const int b = blockIdx.x * 256 + threadIdx.x;
    float sp = 0.f, sm = -1e30f;
#pragma unroll
    for (int r = 0; r < RG; ++r) {
        sp += pp4[r * BN + b];
        sm = fmaxf(sm, pmax[r * BN + b]);
    }
    float n4 = sqrtf(sqrtf(sp));
    n4 = fmaxf(n4, 1e-12f);
    const float inv = 1.0f / n4;
    inv_norm[b] = inv;
    vmax[b] = sm * inv;
}

// Pass 2: partial Z and partial weighted sums per (rowgroup, column)
__global__ __launch_bounds__(256) void k_pass2(const float* __restrict__ x,
                                               const float* __restrict__ cat,
                                               const float* __restrict__ y,
                                               const float* __restrict__ inv_norm,
                                               const float* __restrict__ vmax,
                                               float* __restrict__ pZ,
                                               float* __restrict__ pW) {
    __shared__ float xs[CWG * PAD];
    __shared__ float cs[RT * PAD];
    __shared__ float ysh[RT];
    __shared__ float redA[16 * CWG];
    __shared__ float redB[16 * CWG];

    const int t = threadIdx.x;
    const int colbase = blockIdx.x * CWG;
    const int rowbase = blockIdx.y * ROWS_PER_G;

    for (int li = t * 4; li < CWG * DK; li += 256 * 4) {
        const int c = li >> 7, k = li & 127;
        *reinterpret_cast<float4*>(&xs[c * PAD + k]) =
            ld4(&x[(size_t)(colbase + c) * DK + k]);
    }

    const int cl = t & 15;
    const int rl = t >> 4;

    float inm[4], vmx[4];
#pragma unroll
    for (int j = 0; j < 4; ++j) {
        inm[j] = inv_norm[colbase + cl + 16 * j];
        vmx[j] = vmax[colbase + cl + 16 * j];
    }

    float zacc[4] = {0.f, 0.f, 0.f, 0.f};
    float wacc[4] = {0.f, 0.f, 0.f, 0.f};

    for (int rt0 = 0; rt0 < ROWS_PER_G; rt0 += RT) {
        __syncthreads();
        for (int li = t * 4; li < RT * DK; li += 256 * 4) {
            const int r = li >> 7, k = li & 127;
            *reinterpret_cast<float4*>(&cs[r * PAD + k]) =
                ld4(&cat[(size_t)(rowbase + rt0 + r) * DK + k]);
        }
        if (t < RT) ysh[t] = y[rowbase + rt0 + t];
        __syncthreads();

        float d[4][4] = {};
#pragma unroll 4
        for (int k = 0; k < DK; k += 4) {
            float4 A[4], Bv[4];
#pragma unroll
            for (int i = 0; i < 4; ++i) A[i] = ld4(&cs[(rl * 4 + i) * PAD + k]);
#pragma unroll
            for (int j = 0; j < 4; ++j) Bv[j] = ld4(&xs[(cl + 16 * j) * PAD + k]);
#pragma unroll
            for (int i = 0; i < 4; ++i)
#pragma unroll
                for (int j = 0; j < 4; ++j) fma4(d[i][j], A[i], Bv[j]);
        }
#pragma unroll
        for (int i = 0; i < 4; ++i) {
            const float yr = ysh[rl * 4 + i];
#pragma unroll
            for (int j = 0; j < 4; ++j) {
                const float e = __expf(d[i][j] * inm[j] - vmx[j]);
                zacc[j] += e;
                wacc[j] += yr * e;
            }
        }
    }

    __syncthreads();
#pragma unroll
    for (int j = 0; j < 4; ++j) {
        redA[rl * CWG + cl + 16 * j] = zacc[j];
        redB[rl * CWG + cl + 16 * j] = wacc[j];
    }
    __syncthreads();
    if (t < CWG) {
        float sz = 0.f, sw = 0.f;
#pragma unroll
        for (int r = 0; r < 16; ++r) {
            sz += redA[r * CWG + t];
            sw += redB[r * CWG + t];
        }
        pZ[(size_t)blockIdx.y * BN + colbase + t] = sz;
        pW[(size_t)blockIdx.y * BN + colbase + t] = sw;
    }
}

// Final: combine partials, theta, bias
__global__ __launch_bounds__(256) void k_final(const float* __restrict__ x,
                                               const float* __restrict__ phi,
                                               const float* __restrict__ pZ,
                                               const float* __restrict__ pW,
                                               const float* __restrict__ bias,
                                               float* __restrict__ out) {
    const int b = blockIdx.x * 256 + threadIdx.x;
    float Z = 0.f;
#pragma unroll
    for (int r = 0; r < RG; ++r) Z += pZ[r * BN + b];
    float acc = 0.f;
#pragma unroll
    for (int s = 0; s < SRC; ++s) {
        float dot = 0.f;
        for (int k = 0; k < DK; k += 4) {
            const float4 xv = ld4(&x[(size_t)b * DK + k]);
            const float4 pv = ld4(&phi[s * DK + k]);
            dot += xv.x * pv.x + xv.y * pv.y + xv.z * pv.z + xv.w * pv.w;
        }
        const float th = __expf(dot);
        const float W = pW[(size_t)(2 * s) * BN + b] + pW[(size_t)(2 * s + 1) * BN + b];
        acc += th * W;
    }
    out[b] = acc / Z + bias[0];
}

extern "C" void kernel_launch(void* const* d_in, const int* in_sizes, int n_in,
                              void* d_out, int out_size, void* d_ws, size_t ws_size,
                              hipStream_t stream) {
    const float* x    = (const float*)d_in[0];
    const float* cat  = (const float*)d_in[1];
    const float* y    = (const float*)d_in[2];
    const float* phi  = (const float*)d_in[3];
    const float* bias = (const float*)d_in[4];
    float* out = (float*)d_out;

    float* ws = (float*)d_ws;
    float* pp4      = ws;                  // RG*BN
    float* pmax     = pp4 + RG * BN;       // RG*BN
    float* inv_norm = pmax + RG * BN;      // BN
    float* vmax     = inv_norm + BN;       // BN
    float* pZ       = vmax + BN;           // RG*BN
    float* pW       = pZ + RG * BN;        // RG*BN

    k_pass1<<<dim3(BN / CWG, RG), 256, 0, stream>>>(x, cat, pp4, pmax);
    k_norm<<<BN / 256, 256, 0, stream>>>(pp4, pmax, inv_norm, vmax);
    k_pass2<<<dim3(BN / CWG, RG), 256, 0, stream>>>(x, cat, y, inv_norm, vmax, pZ, pW);
    k_final<<<BN / 256, 256, 0, stream>>>(x, phi, pZ, pW, bias, out);
}

// Round 2
// 73.764 us; speedup vs baseline: 7.3634x; 7.3634x over previous
//
#include <hip/hip_runtime.h>
#include <hip/hip_bf16.h>
#include <math.h>

typedef __bf16 bf16x8 __attribute__((ext_vector_type(8)));
typedef float f32x4 __attribute__((ext_vector_type(4)));

namespace {
constexpr int BN   = 8192;   // batch columns
constexpr int DK   = 128;    // feature dim
constexpr int NCAT = 8192;   // cat rows
constexpr int SRC  = 4;      // source chunks
constexpr int RG   = 8;      // row groups (1024 rows each, 2 per chunk)
constexpr int LDK  = 136;    // padded LDS k-stride (bf16): 272B/row = 17 banks -> 2-way max
}

__device__ __forceinline__ float4 ld4(const float* p) {
    return *reinterpret_cast<const float4*>(p);
}

// fp32 -> bf16 (RNE), 8 elements per thread
__global__ __launch_bounds__(256) void k_convert(const float* __restrict__ in,
                                                 unsigned short* __restrict__ out,
                                                 int n8) {
    const int i = blockIdx.x * 256 + threadIdx.x;
    if (i >= n8) return;
    const float4 a = ld4(in + (size_t)i * 8);
    const float4 b = ld4(in + (size_t)i * 8 + 4);
    float vals[8] = {a.x, a.y, a.z, a.w, b.x, b.y, b.z, b.w};
    union { unsigned short u[8]; uint4 v; } o;
#pragma unroll
    for (int j = 0; j < 8; ++j) {
        __hip_bfloat16 h = __float2bfloat16(vals[j]);
        o.u[j] = *reinterpret_cast<unsigned short*>(&h);
    }
    *reinterpret_cast<uint4*>(&out[(size_t)i * 8]) = o.v;
}

// MFMA pass over a 128-col x 1024-row group.
// PASS==1: outA = partial sum(d^4), outB = partial max(d)
// PASS==2: outA = partial Z, outB = partial sum(y*exp)
template <int PASS>
__global__ __launch_bounds__(256, 2) void k_mfma_pass(
    const unsigned short* __restrict__ xb,    // [BN][DK] bf16
    const unsigned short* __restrict__ catb,  // [NCAT][DK] bf16
    const float* __restrict__ y,
    const float* __restrict__ inv_norm,
    const float* __restrict__ vmax,
    float* __restrict__ outA,
    float* __restrict__ outB) {
    __shared__ __align__(16) unsigned short As[128 * LDK];
    __shared__ __align__(16) unsigned short Bs[128 * LDK];
    __shared__ float ysh[128];
    __shared__ float redA[2][128];
    __shared__ float redB[2][128];

    const int t = threadIdx.x;
    const int colbase = blockIdx.x * 128;
    const int rowgrp = blockIdx.y;            // 0..7
    const int rowbase0 = rowgrp * 1024;

    const int wid = t >> 6;
    const int lane = t & 63;
    const int wr = wid >> 1;                  // row half 0..1
    const int wc = wid & 1;                   // col half 0..1
    const int lr = lane & 15;                 // fragment row/col
    const int kb = lane >> 4;                 // k-block 0..3

    // stage B tile (x): 128 cols x 128 k, resident the whole kernel
#pragma unroll
    for (int q = t; q < 2048; q += 256) {
        const int c = q >> 4, kc = q & 15;
        *reinterpret_cast<uint4*>(&Bs[c * LDK + kc * 8]) =
            *reinterpret_cast<const uint4*>(&xb[(size_t)(colbase + c) * DK + kc * 8]);
    }

    float accA[4], accB[4];
    float inm[4], vmx4[4];
#pragma unroll
    for (int j = 0; j < 4; ++j) {
        accA[j] = 0.f;
        accB[j] = (PASS == 1) ? -3.0e38f : 0.f;
        if (PASS == 2) {
            const int col = colbase + wc * 64 + j * 16 + lr;
            inm[j] = inv_norm[col];
            vmx4[j] = vmax[col];
        }
    }

    for (int rt = 0; rt < 8; ++rt) {
        const int rowbase = rowbase0 + rt * 128;
        __syncthreads();  // prior reads of As done
#pragma unroll
        for (int q = t; q < 2048; q += 256) {
            const int r = q >> 4, kc = q & 15;
            *reinterpret_cast<uint4*>(&As[r * LDK + kc * 8]) =
                *reinterpret_cast<const uint4*>(&catb[(size_t)(rowbase + r) * DK + kc * 8]);
        }
        if (PASS == 2 && t < 128) ysh[t] = y[rowbase + t];
        __syncthreads();

        f32x4 acc[4][4];
#pragma unroll
        for (int i = 0; i < 4; ++i)
#pragma unroll
            for (int j = 0; j < 4; ++j) acc[i][j] = (f32x4){0.f, 0.f, 0.f, 0.f};

#pragma unroll
        for (int kk = 0; kk < 4; ++kk) {
            bf16x8 a[4], b[4];
#pragma unroll
            for (int i = 0; i < 4; ++i)
                a[i] = *reinterpret_cast<const bf16x8*>(
                    &As[(wr * 64 + i * 16 + lr) * LDK + kk * 32 + kb * 8]);
#pragma unroll
            for (int j = 0; j < 4; ++j)
                b[j] = *reinterpret_cast<const bf16x8*>(
                    &Bs[(wc * 64 + j * 16 + lr) * LDK + kk * 32 + kb * 8]);
#pragma unroll
            for (int i = 0; i < 4; ++i)
#pragma unroll
                for (int j = 0; j < 4; ++j)
                    acc[i][j] = __builtin_amdgcn_mfma_f32_16x16x32_bf16(
                        a[i], b[j], acc[i][j], 0, 0, 0);
        }

        if (PASS == 1) {
#pragma unroll
            for (int i = 0; i < 4; ++i)
#pragma unroll
                for (int j = 0; j < 4; ++j)
#pragma unroll
                    for (int r = 0; r < 4; ++r) {
                        const float v = acc[i][j][r];
                        const float v2 = v * v;
                        accA[j] += v2 * v2;
                        accB[j] = fmaxf(accB[j], v);
                    }
        } else {
#pragma unroll
            for (int i = 0; i < 4; ++i)
#pragma unroll
                for (int r = 0; r < 4; ++r) {
                    const float yr = ysh[wr * 64 + i * 16 + kb * 4 + r];
#pragma unroll
                    for (int j = 0; j < 4; ++j) {
                        const float e = __expf(fmaf(acc[i][j][r], inm[j], -vmx4[j]));
                        accA[j] += e;
                        accB[j] += yr * e;
                    }
                }
        }
    }

    // cross-lane reduce over k-block groups (rows live in lane bits 4-5)
#pragma unroll
    for (int j = 0; j < 4; ++j) {
        float a16 = __shfl_xor(accA[j], 16, 64);
        float b16 = __shfl_xor(accB[j], 16, 64);
        accA[j] += a16;
        accB[j] = (PASS == 1) ? fmaxf(accB[j], b16) : accB[j] + b16;
        float a32 = __shfl_xor(accA[j], 32, 64);
        float b32 = __shfl_xor(accB[j], 32, 64);
        accA[j] += a32;
        accB[j] = (PASS == 1) ? fmaxf(accB[j], b32) : accB[j] + b32;
    }

    if (lane < 16) {
#pragma unroll
        for (int j = 0; j < 4; ++j) {
            redA[wr][wc * 64 + j * 16 + lane] = accA[j];
            redB[wr][wc * 64 + j * 16 + lane] = accB[j];
        }
    }
    __syncthreads();
    if (t < 128) {
        const float a = redA[0][t] + redA[1][t];
        const float b = (PASS == 1) ? fmaxf(redB[0][t], redB[1][t])
                                    : redB[0][t] + redB[1][t];
        outA[(size_t)rowgrp * BN + colbase + t] = a;
        outB[(size_t)rowgrp * BN + colbase + t] = b;
    }
}

// Reduce partials -> inv_norm, scaled max
__global__ __launch_bounds__(256) void k_norm(const float* __restrict__ pp4,
                                              const float* __restrict__ pmax,
                                              float* __restrict__ inv_norm,
                                              float* __restrict__ vmax) {
    const int b = blockIdx.x * 256 + threadIdx.x;
    float sp = 0.f, sm = -3.0e38f;
#pragma unroll
    for (int r = 0; r < RG; ++r) {
        sp += pp4[r * BN + b];
        sm = fmaxf(sm, pmax[r * BN + b]);
    }
    float n4 = sqrtf(sqrtf(sp));
    n4 = fmaxf(n4, 1e-12f);
    const float inv = 1.0f / n4;
    inv_norm[b] = inv;
    vmax[b] = sm * inv;
}

// Final: 4 threads per output (one per source), xor-reduce
__global__ __launch_bounds__(256) void k_final(const float* __restrict__ x,
                                               const float* __restrict__ phi,
                                               const float* __restrict__ pZ,
                                               const float* __restrict__ pW,
                                               const float* __restrict__ bias,
                                               float* __restrict__ out) {
    const int g = blockIdx.x * 256 + threadIdx.x;
    const int b = g >> 2, s = g & 3;
    float dot = 0.f;
#pragma unroll
    for (int k = 0; k < DK; k += 4) {
        const float4 xv = ld4(&x[(size_t)b * DK + k]);
        const float4 pv = ld4(&phi[s * DK + k]);
        dot += xv.x * pv.x + xv.y * pv.y + xv.z * pv.z + xv.w * pv.w;
    }
    const float W = pW[(size_t)(2 * s) * BN + b] + pW[(size_t)(2 * s + 1) * BN + b];
    float v = __expf(dot) * W;
    float Z = pZ[(size_t)(2 * s) * BN + b] + pZ[(size_t)(2 * s + 1) * BN + b];
    v += __shfl_xor(v, 1, 64);
    v += __shfl_xor(v, 2, 64);
    Z += __shfl_xor(Z, 1, 64);
    Z += __shfl_xor(Z, 2, 64);
    if (s == 0) out[b] = v / Z + bias[0];
}

extern "C" void kernel_launch(void* const* d_in, const int* in_sizes, int n_in,
                              void* d_out, int out_size, void* d_ws, size_t ws_size,
                              hipStream_t stream) {
    const float* x    = (const float*)d_in[0];
    const float* cat  = (const float*)d_in[1];
    const float* y    = (const float*)d_in[2];
    const float* phi  = (const float*)d_in[3];
    const float* bias = (const float*)d_in[4];
    float* out = (float*)d_out;

    char* ws = (char*)d_ws;
    unsigned short* xb   = (unsigned short*)ws;                    // BN*DK bf16 (2MB)
    unsigned short* catb = xb + (size_t)BN * DK;                   // 2MB
    float* pp4      = (float*)(catb + (size_t)NCAT * DK);          // RG*BN
    float* pmax     = pp4 + (size_t)RG * BN;
    float* inv_norm = pmax + (size_t)RG * BN;                      // BN
    float* vmax     = inv_norm + BN;                               // BN
    float* pZ       = vmax + BN;                                   // RG*BN
    float* pW       = pZ + (size_t)RG * BN;                        // RG*BN

    k_convert<<<(BN * DK / 8 + 255) / 256, 256, 0, stream>>>(x, xb, BN * DK / 8);
    k_convert<<<(NCAT * DK / 8 + 255) / 256, 256, 0, stream>>>(cat, catb, NCAT * DK / 8);
    k_mfma_pass<1><<<dim3(BN / 128, RG), 256, 0, stream>>>(xb, catb, y, nullptr, nullptr,
                                                           pp4, pmax);
    k_norm<<<BN / 256, 256, 0, stream>>>(pp4, pmax, inv_norm, vmax);
    k_mfma_pass<2><<<dim3(BN / 128, RG), 256, 0, stream>>>(xb, catb, y, inv_norm, vmax,
                                                           pZ, pW);
    k_final<<<BN * SRC / 256, 256, 0, stream>>>(x, phi, pZ, pW, bias, out);
}